// Round 3
// baseline (753.211 us; speedup 1.0000x reference)
//
#include <hip/hip_runtime.h>
#include <hip/hip_bf16.h>
#include <stdint.h>

// LPLRQuantizedLinear: B=8192 rows, N=M=4096, rank 64 (48 frozen + 16 ft).
// ALL float tensors are FP32 (per reference); Q_idxs int32; output FP32.
// (Rounds 0-2 NaN root cause: misread fp32 buffers as bf16 -> mantissa bits
// form NaN patterns. Internally we compute in bf16 MFMA; I/O is f32.)
//
// Pipeline:
//   prep     : R_cat[64][4096] bf16 (ws), L_cat -> Wq[:, 4096:4160] bf16
//   decode   : Wq[:, :4096] = bf16(0.02 * grid[Q_idxs])      (f32 grid)
//   fwht_pre : h[:, :4096] = bf16(FWHT(x*SU)/64)             (f32 in, fp32 math)
//   tgemm    : Tpart = h @ R_cat^T (k-split 4, fp32 partials)
//   tconv    : h[:, 4096:4160] = bf16(sum Tpart)
//   mgemm    : d_out = f32( h[8192,4160] @ Wq[4096,4160]^T ) (extended-K NT GEMM)
//   fwht_post: d_out = (FWHT(d_out)/64) * SV                 (f32 in-place)

typedef __bf16 bf16;
typedef __bf16 bf16x8 __attribute__((ext_vector_type(8)));
typedef float f32x4 __attribute__((ext_vector_type(4)));

#define KE 4160
#define KT_MAIN 130
#define NN 4096
#define MM 4096
#define BB 8192

// ---------------- prep: build R_cat (bf16) and L columns of Wq ----------------
__global__ void prep_kernel(const float* __restrict__ Lft, const float* __restrict__ Rft,
                            const float* __restrict__ Lres, const float* __restrict__ Rres,
                            bf16* __restrict__ Rcat, bf16* __restrict__ Wq) {
  int tid = blockIdx.x * 256 + threadIdx.x;   // 524288 total
  if (tid < 64 * 4096) {
    int r = tid >> 12, n = tid & 4095;
    float v = (r < 48) ? Rres[r * 4096 + n] : Rft[(r - 48) * 4096 + n];
    Rcat[tid] = (bf16)v;
  } else {
    int t2 = tid - 64 * 4096;
    int m = t2 >> 6, r = t2 & 63;
    float v = (r < 48) ? Lres[m * 48 + r] : Lft[m * 16 + (r - 48)];
    Wq[(size_t)m * KE + 4096 + r] = (bf16)v;
  }
}

// ---------------- decode: Wq[:, :4096] = bf16(0.02*grid[Q_idxs]) ----------------
__global__ void decode_kernel(const int* __restrict__ qidx, const float* __restrict__ grid,
                              bf16* __restrict__ Wq) {
  int tid = blockIdx.x * 256 + threadIdx.x;   // 4096*512 = 2M
  int m = tid >> 9, g = tid & 511;
  uint32_t idx = (uint32_t)qidx[tid];
  const float4* gp = (const float4*)(grid + (size_t)idx * 8);
  float4 w0 = gp[0], w1 = gp[1];
  bf16x8 o;
  o[0] = (bf16)(w0.x * 0.02f); o[1] = (bf16)(w0.y * 0.02f);
  o[2] = (bf16)(w0.z * 0.02f); o[3] = (bf16)(w0.w * 0.02f);
  o[4] = (bf16)(w1.x * 0.02f); o[5] = (bf16)(w1.y * 0.02f);
  o[6] = (bf16)(w1.z * 0.02f); o[7] = (bf16)(w1.w * 0.02f);
  *(bf16x8*)(Wq + (size_t)m * KE + g * 8) = o;
}

// ---------------- FWHT-4096 row-wise, f32 in -> bf16 out (pre, *SU before) ----------------
__global__ void fwht_pre_kernel(const float* __restrict__ src,
                                bf16* __restrict__ dst,
                                const float* __restrict__ SU) {
  __shared__ float buf[4096];
  const int row = blockIdx.x, t = threadIdx.x;
  const float4* sp = (const float4*)(src + (size_t)row * NN + t * 16);
  const float4* su = (const float4*)(SU + t * 16);
  float v[16];
#pragma unroll
  for (int q = 0; q < 4; ++q) {
    float4 a = sp[q], s = su[q];
    v[q * 4 + 0] = a.x * s.x; v[q * 4 + 1] = a.y * s.y;
    v[q * 4 + 2] = a.z * s.z; v[q * 4 + 3] = a.w * s.w;
  }
#pragma unroll
  for (int s = 1; s < 16; s <<= 1) {
#pragma unroll
    for (int i = 0; i < 16; ++i) {
      if (!(i & s)) { float a = v[i], b = v[i + s]; v[i] = a + b; v[i + s] = a - b; }
    }
  }
#pragma unroll
  for (int i = 0; i < 16; ++i) buf[t * 16 + i] = v[i];
  for (int s = 16; s < 4096; s <<= 1) {
    __syncthreads();
#pragma unroll
    for (int j = 0; j < 8; ++j) {
      int p = t + j * 256;
      int i = ((p & ~(s - 1)) << 1) | (p & (s - 1));
      float a = buf[i], b = buf[i + s];
      buf[i] = a + b; buf[i + s] = a - b;
    }
  }
  __syncthreads();
  bf16x8 o0, o1;
#pragma unroll
  for (int i = 0; i < 8; ++i) {
    o0[i] = (bf16)(buf[t * 16 + i] * 0.015625f);
    o1[i] = (bf16)(buf[t * 16 + 8 + i] * 0.015625f);
  }
  bf16* dp = dst + (size_t)row * KE + t * 16;
  *(bf16x8*)dp = o0;
  *(bf16x8*)(dp + 8) = o1;
}

// ---------------- FWHT-4096 row-wise, f32 in-place (post, *SV after) ----------------
__global__ void fwht_post_kernel(float* __restrict__ data, const float* __restrict__ SV) {
  __shared__ float buf[4096];
  const int row = blockIdx.x, t = threadIdx.x;
  float4* dp = (float4*)(data + (size_t)row * MM + t * 16);
  float v[16];
#pragma unroll
  for (int q = 0; q < 4; ++q) {
    float4 a = dp[q];
    v[q * 4 + 0] = a.x; v[q * 4 + 1] = a.y; v[q * 4 + 2] = a.z; v[q * 4 + 3] = a.w;
  }
#pragma unroll
  for (int s = 1; s < 16; s <<= 1) {
#pragma unroll
    for (int i = 0; i < 16; ++i) {
      if (!(i & s)) { float a = v[i], b = v[i + s]; v[i] = a + b; v[i + s] = a - b; }
    }
  }
#pragma unroll
  for (int i = 0; i < 16; ++i) buf[t * 16 + i] = v[i];
  for (int s = 16; s < 4096; s <<= 1) {
    __syncthreads();
#pragma unroll
    for (int j = 0; j < 8; ++j) {
      int p = t + j * 256;
      int i = ((p & ~(s - 1)) << 1) | (p & (s - 1));
      float a = buf[i], b = buf[i + s];
      buf[i] = a + b; buf[i + s] = a - b;
    }
  }
  __syncthreads();
  const float4* sv = (const float4*)(SV + t * 16);
#pragma unroll
  for (int q = 0; q < 4; ++q) {
    float4 s = sv[q];
    float4 o;
    o.x = buf[t * 16 + q * 4 + 0] * 0.015625f * s.x;
    o.y = buf[t * 16 + q * 4 + 1] * 0.015625f * s.y;
    o.z = buf[t * 16 + q * 4 + 2] * 0.015625f * s.z;
    o.w = buf[t * 16 + q * 4 + 3] * 0.015625f * s.w;
    dp[q] = o;
  }
}

// ---------------- tgemm: Tpart[split] = h @ R_cat^T ----------------
__global__ void __launch_bounds__(256) tgemm_kernel(const bf16* __restrict__ A,
                                                    const bf16* __restrict__ Bm,
                                                    float* __restrict__ Tpart) {
  __shared__ bf16 lA[128 * 32];
  __shared__ bf16 lB[64 * 32];
  const int t = threadIdx.x, w = t >> 6, l = t & 63;
  const int bmBlk = blockIdx.x;   // 64 row blocks
  const int split = blockIdx.y;   // 4 k-splits
  const int wm = w >> 1, wn = w & 1;
  f32x4 acc[4][2] = {};
  const int arow = t >> 1, acol = (t & 1) * 16;            // A staging: 128 rows x 32
  const bf16* pa = A + (size_t)(bmBlk * 128 + arow) * KE + acol;
  const int brow = (t & 127) >> 1, bcol = acol;            // B staging: 64 rows x 32
  const bf16* pb = Bm + (size_t)brow * 4096 + bcol;
  const int fr = l & 15, fk = (l >> 4) * 8;
  for (int kt = 0; kt < 32; ++kt) {
    const int k0 = (split * 32 + kt) * 32;
    bf16x8 a0 = *(const bf16x8*)(pa + k0);
    bf16x8 a1 = *(const bf16x8*)(pa + k0 + 8);
    *(bf16x8*)&lA[arow * 32 + acol] = a0;
    *(bf16x8*)&lA[arow * 32 + acol + 8] = a1;
    if (t < 128) {
      bf16x8 b0 = *(const bf16x8*)(pb + k0);
      bf16x8 b1 = *(const bf16x8*)(pb + k0 + 8);
      *(bf16x8*)&lB[brow * 32 + bcol] = b0;
      *(bf16x8*)&lB[brow * 32 + bcol + 8] = b1;
    }
    __syncthreads();
    bf16x8 af[4], bfr[2];
#pragma unroll
    for (int i = 0; i < 4; ++i) af[i] = *(const bf16x8*)&lA[(wm * 64 + i * 16 + fr) * 32 + fk];
#pragma unroll
    for (int i = 0; i < 2; ++i) bfr[i] = *(const bf16x8*)&lB[(wn * 32 + i * 16 + fr) * 32 + fk];
#pragma unroll
    for (int mi = 0; mi < 4; ++mi)
#pragma unroll
      for (int ni = 0; ni < 2; ++ni)
        acc[mi][ni] = __builtin_amdgcn_mfma_f32_16x16x32_bf16(af[mi], bfr[ni], acc[mi][ni], 0, 0, 0);
    __syncthreads();
  }
  float* out = Tpart + (size_t)split * BB * 64;
  const int orow = bmBlk * 128 + wm * 64 + (l >> 4) * 4;
  const int ocol = wn * 32 + (l & 15);
#pragma unroll
  for (int mi = 0; mi < 4; ++mi)
#pragma unroll
    for (int ni = 0; ni < 2; ++ni)
#pragma unroll
      for (int r = 0; r < 4; ++r)
        out[(size_t)(orow + mi * 16 + r) * 64 + ocol + ni * 16] = acc[mi][ni][r];
}

__global__ void tconv_kernel(const float* __restrict__ Tpart, bf16* __restrict__ h) {
  int i = blockIdx.x * 256 + threadIdx.x;   // 8192*64
  float s = Tpart[i] + Tpart[i + BB * 64] + Tpart[i + 2 * BB * 64] + Tpart[i + 3 * BB * 64];
  int row = i >> 6, c = i & 63;
  h[(size_t)row * KE + 4096 + c] = (bf16)s;
}

// ---------------- mgemm: C[8192,4096] f32 = A[8192,4160] @ B[4096,4160]^T ----------------
__global__ void __launch_bounds__(256) mgemm_kernel(const bf16* __restrict__ A,
                                                    const bf16* __restrict__ B,
                                                    float* __restrict__ C) {
  __shared__ bf16 lA[128 * 32];
  __shared__ bf16 lB[128 * 32];
  const int t = threadIdx.x, w = t >> 6, l = t & 63;
  const int bn = blockIdx.x, bm = blockIdx.y;
  const int wm = w >> 1, wn = w & 1;
  f32x4 acc[4][4] = {};
  const int srow = t >> 1, scol = (t & 1) * 16;
  const bf16* pa = A + (size_t)(bm * 128 + srow) * KE + scol;
  const bf16* pb = B + (size_t)(bn * 128 + srow) * KE + scol;
  const int fr = l & 15, fk = (l >> 4) * 8;
  for (int kt = 0; kt < KT_MAIN; ++kt) {
    const int k0 = kt * 32;
    bf16x8 a0 = *(const bf16x8*)(pa + k0);
    bf16x8 a1 = *(const bf16x8*)(pa + k0 + 8);
    bf16x8 b0 = *(const bf16x8*)(pb + k0);
    bf16x8 b1 = *(const bf16x8*)(pb + k0 + 8);
    *(bf16x8*)&lA[srow * 32 + scol] = a0;
    *(bf16x8*)&lA[srow * 32 + scol + 8] = a1;
    *(bf16x8*)&lB[srow * 32 + scol] = b0;
    *(bf16x8*)&lB[srow * 32 + scol + 8] = b1;
    __syncthreads();
    bf16x8 af[4], bfr[4];
#pragma unroll
    for (int i = 0; i < 4; ++i) {
      af[i] = *(const bf16x8*)&lA[(wm * 64 + i * 16 + fr) * 32 + fk];
      bfr[i] = *(const bf16x8*)&lB[(wn * 64 + i * 16 + fr) * 32 + fk];
    }
#pragma unroll
    for (int mi = 0; mi < 4; ++mi)
#pragma unroll
      for (int ni = 0; ni < 4; ++ni)
        acc[mi][ni] = __builtin_amdgcn_mfma_f32_16x16x32_bf16(af[mi], bfr[ni], acc[mi][ni], 0, 0, 0);
    __syncthreads();
  }
  const int orow = bm * 128 + wm * 64 + (l >> 4) * 4;
  const int ocol = bn * 128 + wn * 64 + (l & 15);
#pragma unroll
  for (int mi = 0; mi < 4; ++mi)
#pragma unroll
    for (int ni = 0; ni < 4; ++ni)
#pragma unroll
      for (int r = 0; r < 4; ++r)
        C[(size_t)(orow + mi * 16 + r) * MM + ocol + ni * 16] = acc[mi][ni][r];
}

extern "C" void kernel_launch(void* const* d_in, const int* in_sizes, int n_in,
                              void* d_out, int out_size, void* d_ws, size_t ws_size,
                              hipStream_t stream) {
  const float* x    = (const float*)d_in[0];
  const float* SU   = (const float*)d_in[1];
  const float* SV   = (const float*)d_in[2];
  const float* grid = (const float*)d_in[3];
  const float* Lft  = (const float*)d_in[4];
  const float* Rft  = (const float*)d_in[5];
  const float* Lres = (const float*)d_in[6];
  const float* Rres = (const float*)d_in[7];
  const int*   qidx = (const int*)d_in[10];
  float* out = (float*)d_out;

  char* ws = (char*)d_ws;
  bf16*  h     = (bf16*)ws;                                   // 8192*4160*2 = 68,157,440
  bf16*  Wq    = (bf16*)(ws + 68157440);                      // 4096*4160*2 = 34,078,720
  bf16*  Rcat  = (bf16*)(ws + 68157440 + 34078720);           // 64*4096*2   =    524,288
  float* Tpart = (float*)(ws + 68157440 + 34078720 + 524288); // 4*8192*64*4 =  8,388,608

  prep_kernel<<<2048, 256, 0, stream>>>(Lft, Rft, Lres, Rres, Rcat, Wq);
  decode_kernel<<<8192, 256, 0, stream>>>(qidx, grid, Wq);
  fwht_pre_kernel<<<8192, 256, 0, stream>>>(x, h, SU);
  tgemm_kernel<<<dim3(64, 4), 256, 0, stream>>>(h, Rcat, Tpart);
  tconv_kernel<<<2048, 256, 0, stream>>>(Tpart, h);
  mgemm_kernel<<<dim3(32, 64), 256, 0, stream>>>(h, Wq, out);
  fwht_post_kernel<<<8192, 256, 0, stream>>>(out, SV);
}